// Round 12
// baseline (1195.817 us; speedup 1.0000x reference)
//
#include <hip/hip_runtime.h>
#include <hip/hip_bf16.h>
#include <math.h>

#define NN 3
#define BB 4
#define CC 256
#define C2 512
#define HH 40
#define WW 40
#define PP 1600
#define NBB 12                  // NN*BB
#define NODESZ (NBB*CC*PP)      // 4,915,200
#define TO 16                   // theta: output channels per block
#define PAD 1764                // 42*42 padded pixels

typedef short short8 __attribute__((ext_vector_type(8)));
typedef float f32x4 __attribute__((ext_vector_type(4)));
typedef unsigned short ushort_t;
typedef unsigned int uint_t;

__device__ __forceinline__ ushort_t f2bf(float x) {
  union { float f; uint_t u; } v; v.f = x;
  uint_t r = v.u + 0x7fff + ((v.u >> 16) & 1);
  return (ushort_t)(r >> 16);
}

__device__ __forceinline__ void async_ld16(const ushort_t* g, ushort_t* l) {
  __builtin_amdgcn_global_load_lds(
      (const __attribute__((address_space(1))) uint_t*)g,
      (__attribute__((address_space(3))) uint_t*)l, 16, 0, 0);
}

__global__ void k_copy(const float* __restrict__ in, float* __restrict__ out) {
  int i = blockIdx.x * 256 + threadIdx.x;
  out[i] = in[i];
}

// th_t[nb][p][c] (bf16) = tb[o] + sum_c tw[o,c] * nodes[nb,c,p]
__global__ void k_theta(const float* __restrict__ nodes, const float* __restrict__ tw,
                        const float* __restrict__ tb, ushort_t* __restrict__ th_t) {
  __shared__ float w[TO * CC];
  int t = threadIdx.x;
  int nb = blockIdx.y / (CC / TO);
  int o0 = (blockIdx.y % (CC / TO)) * TO;
  for (int i = t; i < TO * CC; i += 320) w[i] = tw[(o0 + (i >> 8)) * CC + (i & 255)];
  __syncthreads();
  int p = blockIdx.x * 320 + t;
  const float* src = nodes + nb * CC * PP + p;
  float acc[TO];
#pragma unroll
  for (int o = 0; o < TO; ++o) acc[o] = tb[o0 + o];
  for (int c = 0; c < CC; c += 4) {
    float v0 = src[c * PP], v1 = src[(c + 1) * PP], v2 = src[(c + 2) * PP], v3 = src[(c + 3) * PP];
#pragma unroll
    for (int o = 0; o < TO; ++o) {
      const float4 ww = *(const float4*)(w + o * CC + c);
      acc[o] += ww.x * v0 + ww.y * v1 + ww.z * v2 + ww.w * v3;
    }
  }
  size_t base = ((size_t)nb * PP + p) * CC + o0;
#pragma unroll
  for (int o = 0; o < TO; o += 2) {
    uint_t lo = f2bf(acc[o]), hi = f2bf(acc[o + 1]);
    *(uint_t*)&th_t[base + o] = lo | (hi << 16);
  }
}

// nodes [12][256][1600] fp32 -> nodes_bf_t [12][1600][256] bf16 (transpose),
// with 16B-chunk XOR swizzle within each row: c' = c ^ ((q&7)<<3).
// (Consumed only by k_attn_mfma, which un-XORs on its LDS frag reads.)
__global__ void k_to_bf_t(const float* __restrict__ src, ushort_t* __restrict__ dst) {
  __shared__ float tile[32][33];
  int nb = blockIdx.z;
  int c0 = blockIdx.y * 32;
  int pp0 = blockIdx.x * 32;
  int tx = threadIdx.x & 31, ty = threadIdx.x >> 5;
#pragma unroll
  for (int i = 0; i < 4; ++i)
    tile[ty + 8 * i][tx] = src[((size_t)nb * CC + c0 + ty + 8 * i) * PP + pp0 + tx];
  __syncthreads();
#pragma unroll
  for (int i = 0; i < 4; ++i) {
    int q = pp0 + ty + 8 * i;
    int c = c0 + tx;
    int cs = c ^ ((q & 7) << 3);
    dst[((size_t)nb * PP + q) * CC + cs] = f2bf(tile[tx][ty + 8 * i]);
  }
}

// vf frag-major bf16: vf[eb][T][nt][lane(quad,l16)][j]
//   = nodes[recv][c][p] + nodes[send][c][p],  c = 16nt + l16, p = 32T + quad*8 + j
// Each (T,nt) PV B-fragment = contiguous 1KB, one coalesced load in attn.
__global__ void k_prep_vf(const float* __restrict__ nodes, ushort_t* __restrict__ vf) {
  int T = blockIdx.x;                   // 0..49
  int eb = blockIdx.y;                  // 0..23
  int e = eb >> 2, b = eb & 3;
  int n = e >> 1, jidx = e & 1;
  int js = jidx + (jidx >= n ? 1 : 0);
  const float* s0 = nodes + (size_t)(n * BB + b) * CC * PP;
  const float* s1 = nodes + (size_t)(js * BB + b) * CC * PP;
  ushort_t* dst = vf + ((size_t)eb * 50 + T) * 8192;
  int t = threadIdx.x;
#pragma unroll
  for (int k = 0; k < 4; ++k) {
    int cid = t + 256 * k;              // 0..1023 (16 nt x 64 lanes)
    int nt = cid >> 6, l = cid & 63;
    int quad = l >> 4, l16 = l & 15;
    int c = 16 * nt + l16;
    int p = 32 * T + quad * 8;
    const float4* a0 = (const float4*)(s0 + (size_t)c * PP + p);
    const float4* a1 = (const float4*)(s1 + (size_t)c * PP + p);
    float4 x0 = a0[0], x1 = a0[1];
    float4 y0 = a1[0], y1 = a1[1];
    short8 o;
    o[0] = (short)f2bf(x0.x + y0.x); o[1] = (short)f2bf(x0.y + y0.y);
    o[2] = (short)f2bf(x0.z + y0.z); o[3] = (short)f2bf(x0.w + y0.w);
    o[4] = (short)f2bf(x1.x + y1.x); o[5] = (short)f2bf(x1.y + y1.y);
    o[6] = (short)f2bf(x1.z + y1.z); o[7] = (short)f2bf(x1.w + y1.w);
    *(short8*)(dst + (size_t)cid * 8) = o;
  }
}

// Flash attention, 64-p block, 4 waves, swapped-S softmax, XCD-swizzled.
// (unchanged from R8-R10; at its byte floor ~1.04GB / ~10TB/s.)
__global__ __launch_bounds__(256, 2) void k_attn_mfma(
    const ushort_t* __restrict__ nodes_bf_t,  // [12][1600][256] chunk-swizzled
    const ushort_t* __restrict__ th_t,        // [12][1600][256] plain
    const ushort_t* __restrict__ vf,          // [24][50][16][512] frag-major
    float* __restrict__ agg_t)                // [2][12][1600][256]
{
  __shared__ ushort_t Ej[32 * 256];   // 16 KB
  __shared__ ushort_t Sp[64 * 40];    // 5 KB (rows padded to 40 u16 = 80B)
  __shared__ float Al[64];
  __shared__ float Linv[64];

  const int t = threadIdx.x;
  const int w = t >> 6;               // 0..3
  const int l = t & 63;
  const int quad = l >> 4;
  const int l16 = l & 15;
  // ---- XCD-aware remap (perf-only; mapping assumption xcd = flat%8) ----
  const int F = blockIdx.x + 25 * (blockIdx.y + 12 * blockIdx.z);
  const int wk = (F & 7) * 75 + (F >> 3);        // bijective: 600 = 8*75
  const int p0 = (wk % 25) * 64;
  const int nb = (wk / 25) % 12;
  const int jidx = wk / 300;
  const int n = nb >> 2, b = nb & 3;
  const int e = n * 2 + jidx;
  const int js = jidx + (jidx >= n ? 1 : 0);
  const int eb = e * BB + b;

  const ushort_t* ejb = nodes_bf_t + ((size_t)(js * BB + b) * PP) * CC;  // [q][c-swz]
  const ushort_t* vbase = vf + (size_t)eb * 50 * 8192;

  // th B-frags for this wave's rows p = p0 + 16w + l16 (resident all iters)
  short8 Ath[8];
  {
    const ushort_t* arow = th_t + ((size_t)nb * PP + p0 + 16 * w + l16) * CC + quad * 8;
#pragma unroll
    for (int ks = 0; ks < 8; ++ks) Ath[ks] = *(const short8*)(arow + ks * 32);
  }

  float M = -3.0e38f, Lr = 0.f;       // per-lane: this lane's p-row state
  f32x4 O[4][4];
#pragma unroll
  for (int mt = 0; mt < 4; ++mt)
#pragma unroll
    for (int nt = 0; nt < 4; ++nt)
#pragma unroll
      for (int r = 0; r < 4; ++r) O[mt][nt][r] = 0.f;

  // prologue: stage q-tile 0 (16 chunks of 1KB, wave w does 4)
#pragma unroll
  for (int i = 0; i < 4; ++i)
    async_ld16(ejb + (4 * w + i) * 512 + l * 8, &Ej[(4 * w + i) * 512]);

  for (int T = 0; T < 50; ++T) {
    __syncthreads();   // A: Ej[T] landed (barrier drains vmcnt); Sp/Al free
    // V frags for this iter (coalesced 1KB each); vmcnt-covered by S+softmax
    short8 Bv[4];
    {
      const ushort_t* vt = vbase + (size_t)T * 8192;
#pragma unroll
      for (int nt = 0; nt < 4; ++nt)
        Bv[nt] = *(const short8*)(vt + (4 * w + nt) * 512 + l * 8);
    }
    // ---- swapped S-GEMM: S^T[q][p], rows q = quad*4+r (+16), cols p = l16 ----
    f32x4 S0, S1;
#pragma unroll
    for (int r = 0; r < 4; ++r) { S0[r] = 0.f; S1[r] = 0.f; }
#pragma unroll
    for (int ks = 0; ks < 8; ++ks) {
      int ch0 = (((ks * 4 + quad) ^ (l16 & 7)) << 3);
      short8 A0 = *(const short8*)(Ej + l16 * CC + ch0);
      short8 A1 = *(const short8*)(Ej + (16 + l16) * CC + ch0);
      S0 = __builtin_amdgcn_mfma_f32_16x16x32_bf16(A0, Ath[ks], S0, 0, 0, 0);
      S1 = __builtin_amdgcn_mfma_f32_16x16x32_bf16(A1, Ath[ks], S1, 0, 0, 0);
    }
    // ---- softmax: 8 in-lane q-values for p = p0+16w+l16; reduce across quads ----
    float m = fmaxf(fmaxf(fmaxf(S0[0], S0[1]), fmaxf(S0[2], S0[3])),
                    fmaxf(fmaxf(S1[0], S1[1]), fmaxf(S1[2], S1[3])));
    m = fmaxf(m, __shfl_xor(m, 16));
    m = fmaxf(m, __shfl_xor(m, 32));
    float Mn = fmaxf(M, m);
    float al = __expf(M - Mn);
    float e0 = __expf(S0[0] - Mn), e1 = __expf(S0[1] - Mn);
    float e2 = __expf(S0[2] - Mn), e3 = __expf(S0[3] - Mn);
    float e4 = __expf(S1[0] - Mn), e5 = __expf(S1[1] - Mn);
    float e6 = __expf(S1[2] - Mn), e7 = __expf(S1[3] - Mn);
    float s = ((e0 + e1) + (e2 + e3)) + ((e4 + e5) + (e6 + e7));
    s += __shfl_xor(s, 16);
    s += __shfl_xor(s, 32);
    Lr = Lr * al + s;
    M = Mn;
    {
      uint2 u;
      u.x = (uint_t)f2bf(e0) | ((uint_t)f2bf(e1) << 16);
      u.y = (uint_t)f2bf(e2) | ((uint_t)f2bf(e3) << 16);
      *(uint2*)&Sp[(16 * w + l16) * 40 + quad * 4] = u;
      uint2 v;
      v.x = (uint_t)f2bf(e4) | ((uint_t)f2bf(e5) << 16);
      v.y = (uint_t)f2bf(e6) | ((uint_t)f2bf(e7) << 16);
      *(uint2*)&Sp[(16 * w + l16) * 40 + 16 + quad * 4] = v;
      if (quad == 0) Al[16 * w + l16] = al;
    }
    __syncthreads();   // B: Sp/Al visible; all waves done reading Ej
    // restage Ej for T+1 (nobody reads Ej until next A, which drains vmcnt)
    if (T < 49) {
#pragma unroll
      for (int i = 0; i < 4; ++i)
        async_ld16(ejb + (size_t)(T + 1) * 8192 + (4 * w + i) * 512 + l * 8,
                   &Ej[(4 * w + i) * 512]);
    }
    // ---- rescale O (alpha of row 16mt+quad*4+r via Al broadcast reads) ----
#pragma unroll
    for (int mt = 0; mt < 4; ++mt) {
      f32x4 a4 = *(const f32x4*)&Al[16 * mt + quad * 4];
#pragma unroll
      for (int nt = 0; nt < 4; ++nt)
#pragma unroll
        for (int r = 0; r < 4; ++r) O[mt][nt][r] *= a4[r];
    }
    // ---- PV: O[p=16mt+quad*4+r][c=64w+16nt+l16] ----
#pragma unroll
    for (int mt = 0; mt < 4; ++mt) {
      short8 Ap = *(const short8*)&Sp[(16 * mt + l16) * 40 + quad * 8];
#pragma unroll
      for (int nt = 0; nt < 4; ++nt)
        O[mt][nt] = __builtin_amdgcn_mfma_f32_16x16x32_bf16(Ap, Bv[nt], O[mt][nt], 0, 0, 0);
    }
  }
  // ---- publish 1/L, then epilogue ----
  __syncthreads();
  if (quad == 0) Linv[16 * w + l16] = 1.f / Lr;
  __syncthreads();
  float* ao = agg_t + (((size_t)jidx * NBB + nb) * PP + p0) * CC;
#pragma unroll
  for (int mt = 0; mt < 4; ++mt) {
    f32x4 li = *(const f32x4*)&Linv[16 * mt + quad * 4];
#pragma unroll
    for (int r = 0; r < 4; ++r) {
      float* dst = ao + (size_t)(16 * mt + quad * 4 + r) * CC + 64 * w + l16;
#pragma unroll
      for (int nt = 0; nt < 4; ++nt) dst[16 * nt] = O[mt][nt][r] * li[r];
    }
  }
}

// ---- conv prep ----

// reorder conv weights [M][512][3][3] fp32 -> [M][9][512] bf16
__global__ void k_wrep(const float* __restrict__ w, ushort_t* __restrict__ wr) {
  int i = blockIdx.x * 256 + threadIdx.x;   // M*9*512
  int ci = i & 511;
  int rest = i >> 9;                        // co*9 + tap
  int tp = rest % 9, co = rest / 9;
  wr[i] = f2bf(w[((size_t)co * 512 + ci) * 9 + tp]);
}

__global__ void k_pad_zero(ushort_t* __restrict__ xpad) {
  int i = blockIdx.x * 256 + threadIdx.x;   // 12*1764*512
  xpad[i] = 0;
}

// interior rows, ch 0..255 <- agg_t[0]+agg_t[1]  (both already [px][c])
__global__ void k_pad_agg(const float* __restrict__ agg_t, ushort_t* __restrict__ xpad) {
  int i = blockIdx.x * 256 + threadIdx.x;   // 12*1600*256
  int c = i & 255;
  int rest = i >> 8;
  int px = rest % PP, nb = rest / PP;
  int y = px / 40, x = px - y * 40;
  size_t src = ((size_t)nb * PP + px) * CC + c;
  float v = agg_t[src] + agg_t[(size_t)NBB * PP * CC + src];
  xpad[((size_t)nb * PAD + (y + 1) * 42 + (x + 1)) * C2 + c] = f2bf(v);
}

// interior rows, ch 256..511 <- transpose of srcA [nb][256][1600]
// MODE 0: val = h[c][px];  MODE 1: val = h[c][px] * r[c][px]
template <int MODE>
__global__ void k_pad_tr(const float* __restrict__ srcA, const float* __restrict__ srcB,
                         ushort_t* __restrict__ xpad) {
  __shared__ float tile[32][33];
  int nb = blockIdx.z;
  int c0 = blockIdx.y * 32;
  int pp0 = blockIdx.x * 32;
  int tx = threadIdx.x & 31, ty = threadIdx.x >> 5;
#pragma unroll
  for (int i = 0; i < 4; ++i) {
    int c = c0 + ty + 8 * i;
    float v = srcA[((size_t)nb * CC + c) * PP + pp0 + tx];
    if (MODE == 1) v *= srcB[((size_t)nb * C2 + c) * PP + pp0 + tx];  // r-gate
    tile[ty + 8 * i][tx] = v;
  }
  __syncthreads();
#pragma unroll
  for (int i = 0; i < 4; ++i) {
    int px = pp0 + ty + 8 * i;
    int y = px / 40, x = px - y * 40;
    xpad[((size_t)nb * PAD + (y + 1) * 42 + (x + 1)) * C2 + CC + c0 + tx] =
        f2bf(tile[tx][ty + 8 * i]);
  }
}

// Implicit-GEMM conv3x3, M=co, N=px(1600), K=9 taps x 512 ci.
// Block: 128co x 128px, 4 waves (2x2), each 64x64 (4x4 16x16x32 frags).
//
// R11 post-mortem: 3-tap barriers at 80KB LDS -> only 1 block/CU (reserved
// LDS; 2x80 = whole pool) -> lost the 2nd barrier domain -> 169us. REVERTED
// to R10 geometry (taps-inner, 2 barriers-domains, slab reuse).
// R12 = R10 + T4 counted-vmcnt (the drain, not the barrier, was the stall):
//  - A triple-buffered (24KB): A(i) staged at iter i-2 -> 2 compute phases
//    (~800cy) of cover instead of 1 (~400cy) vs ~200-500cy L1/L2 latency.
//  - raw s_barrier + exact s_waitcnt vmcnt(N): allowed-remaining = previous
//    iter's issues (per-wave FIFO ledger; A=2/iter, B=4 at tap0):
//    N = 6 at tap1 (cc<15), 0 at (15,8), else 2. All wave-uniform.
//  - sched_barrier(0) after the barrier pins LDS reads behind it (rule #18).
//  - Compiler reordering of stage-issues only tightens the wait (safe).
// LDS 24+32 = 56KB -> 2 blocks/CU (112 <= 160; R11 lesson). Accumulation
// order identical to R10 -> same numerics.
//
// ACT 0: out = sigmoid(acc+bias) -> gates [nb][512][1600]
// ACT 1: v = tanh(acc+bias); z = zsrc[256+co]; out(nodes) = (1-z)h + z*v
template <int ACT>
__global__ __launch_bounds__(256) void k_conv_mfma(
    const ushort_t* __restrict__ xpad,   // [12][1764][512]
    const ushort_t* __restrict__ wr,     // [M][9*512]
    const float* __restrict__ bias,      // [M]
    const float* __restrict__ zsrc,      // gates (ACT1)
    float* __restrict__ out)
{
  __shared__ ushort_t Asm[3][128 * 32];   // 3 x 8 KB  (A: 128co x 32ch, triple)
  __shared__ ushort_t Bsl[2][256 * 32];   // 2 x 16 KB (B slab: 256px x 32ch)
  const int t = threadIdx.x;
  const int w = t >> 6, l = t & 63, quad = l >> 4, l16 = l & 15;
  // ---- XCD-aware remap (perf-only) ----
  const int gy = gridDim.y;                       // 4 (gates) or 2 (cand)
  const int F = blockIdx.x + 13 * (blockIdx.y + gy * blockIdx.z);
  const int cpx = (13 * gy * 12) >> 3;            // 78 or 39
  const int wk = (F & 7) * cpx + (F >> 3);        // bijective: nwg%8==0
  const int xw = wk % 13;
  const int rest = wk / 13;
  const int nb = rest % 12;
  const int m0 = (rest / 12) * 128;
  const int px0 = xw * 128;
  const int wm = (w >> 1) * 64, wn = (w & 1) * 64;

  // --- A staging source: lane l covers rows 32w+lr, +16 (R9 pattern) ---
  const int lr = l >> 2;
  const int swf = (lr ^ (lr >> 2)) & 3;          // fill-side XOR swizzle
  const int lk = ((l & 3) ^ swf) * 8;            // k-part (shorts)
  const ushort_t* wsrc = wr + (size_t)(m0 + 32 * w + lr) * 4608 + lk;

  // --- B slab staging source: wave w covers slab rows [64w, 64w+64) ---
  const int slab0 = px0 + 2 * (px0 / 40);
  const int sgm = ((l >> 2) ^ (l >> 4)) & 3;
  const ushort_t* bslab_src =
      xpad + ((size_t)nb * PAD + slab0 + 64 * w + (l >> 2)) * C2 + ((l & 3) ^ sgm) * 8;

  // --- per-lane B-frag slab rows ---
  int pb[4];
#pragma unroll
  for (int nt = 0; nt < 4; ++nt) {
    int px = px0 + wn + nt * 16 + l16;
    pb[nt] = px + 2 * (px / 40) - slab0;
  }

  // --- A frag-read swizzle ---
  const int swr = (l16 ^ (l16 >> 2)) & 3;
  const int fk = ((quad ^ swr) * 8);

  f32x4 acc[4][4];
#pragma unroll
  for (int mt = 0; mt < 4; ++mt)
#pragma unroll
    for (int nt = 0; nt < 4; ++nt)
#pragma unroll
      for (int r = 0; r < 4; ++r) acc[mt][nt][r] = 0.f;

  // stage A for flat it = cc*9 + tap into buf (2 loads/wave)
  auto stageA = [&](int buf, int it) {
    int ci = it / 9;
    int tap = it - ci * 9;
    const ushort_t* s = wsrc + tap * 512 + ci * 32;
    async_ld16(s, &Asm[buf][w * 1024]);
    async_ld16(s + 16 * 4608, &Asm[buf][w * 1024 + 512]);
  };
  // stage B slab for c-chunk cc (4 loads/wave)
  auto stageB = [&](int buf, int cc) {
    const ushort_t* s = bslab_src + cc * 32;
#pragma unroll
    for (int i = 0; i < 4; ++i)
      async_ld16(s + (size_t)i * 16 * C2, &Bsl[buf][w * 2048 + i * 512]);
  };

  // prologue: B(0), A(0), A(1) in flight (per-wave FIFO order matters)
  stageB(0, 0);
  stageA(0, 0);
  stageA(1, 1);
#pragma unroll 1
  for (int cc = 0; cc < 16; ++cc) {
#pragma unroll
    for (int tap = 0; tap < 9; ++tap) {
      // T4 counted-vmcnt barrier: allowed-remaining = prev iter's issues.
      // FIFO drain (m135): the N newest stay in flight; older (this iter's
      // A, and B for this cc) are forced complete before s_barrier.
      if (tap == 1) {
        if (cc < 15) { asm volatile("s_waitcnt vmcnt(6)" ::: "memory"); }
        else         { asm volatile("s_waitcnt vmcnt(2)" ::: "memory"); }
      } else if (tap == 8) {
        if (cc < 15) { asm volatile("s_waitcnt vmcnt(2)" ::: "memory"); }
        else         { asm volatile("s_waitcnt vmcnt(0)" ::: "memory"); }
      } else {
        asm volatile("s_waitcnt vmcnt(2)" ::: "memory");
      }
      __builtin_amdgcn_s_barrier();
      __builtin_amdgcn_sched_barrier(0);
      const int it = cc * 9 + tap;
      if (it + 2 < 144) stageA((tap + 2) % 3, it + 2);   // (it+2)%3 == (tap+2)%3
      if (tap == 0 && cc + 1 < 16) stageB((cc + 1) & 1, cc + 1);
      const int ky = tap / 3;
      const int toff = ky * 42 + (tap - 3 * ky);
      short8 Af[4], Bf[4];
#pragma unroll
      for (int mt = 0; mt < 4; ++mt)
        Af[mt] = *(const short8*)(&Asm[tap % 3][0] + (wm + mt * 16 + l16) * 32 + fk);
#pragma unroll
      for (int nt = 0; nt < 4; ++nt) {
        int R = pb[nt] + toff;
        Bf[nt] = *(const short8*)(&Bsl[cc & 1][0] + R * 32 + ((quad ^ ((R ^ (R >> 2)) & 3)) << 3));
      }
#pragma unroll
      for (int mt = 0; mt < 4; ++mt)
#pragma unroll
        for (int nt = 0; nt < 4; ++nt)
          acc[mt][nt] = __builtin_amdgcn_mfma_f32_16x16x32_bf16(Af[mt], Bf[nt], acc[mt][nt], 0, 0, 0);
    }
  }

  // --- epilogue ---
#pragma unroll
  for (int mt = 0; mt < 4; ++mt) {
#pragma unroll
    for (int r = 0; r < 4; ++r) {
      int co = m0 + wm + mt * 16 + quad * 4 + r;
      float bv = bias[co];
#pragma unroll
      for (int nt = 0; nt < 4; ++nt) {
        int px = px0 + wn + nt * 16 + l16;
        if (px >= PP) continue;
        float v = acc[mt][nt][r] + bv;
        if (ACT == 0) {
          out[((size_t)nb * C2 + co) * PP + px] = 1.f / (1.f + __expf(-v));
        } else {
          v = tanhf(v);
          float z = zsrc[((size_t)nb * C2 + CC + co) * PP + px];
          float* hp = out + ((size_t)nb * CC + co) * PP + px;
          float h = *hp;
          *hp = (1.f - z) * h + z * v;
        }
      }
    }
  }
}

extern "C" void kernel_launch(void* const* d_in, const int* in_sizes, int n_in,
                              void* d_out, int out_size, void* d_ws, size_t ws_size,
                              hipStream_t stream) {
  const float* nodes_in = (const float*)d_in[0];
  const float* tw = (const float*)d_in[1];
  const float* tb = (const float*)d_in[2];
  const float* gw = (const float*)d_in[3];
  const float* gb = (const float*)d_in[4];
  const float* cw = (const float*)d_in[5];
  const float* cb = (const float*)d_in[6];

  float* nodes = (float*)d_out;                      // fp32 state [12][256][1600]
  char* ws = (char*)d_ws;
  // ---- layout (ws >= 98.3 MB) ----
  // attn phase: R0 nodes_bf_t 9.83 | R1 th_t 9.83 | R2 vf 19.66 | R3 agg_t 39.32
  // conv phase: R1+R2 xh_pad 21.68 | R3 gates 39.32
  // persistent:  78.64.. w_g_r 4.72 | 83.36.. w_c_r 2.36   (pass-invariant)
  ushort_t* nodes_bf_t = (ushort_t*)ws;
  ushort_t* th_t  = (ushort_t*)(ws + 9830400);
  ushort_t* vf    = (ushort_t*)(ws + 19660800);
  float*    agg_t = (float*)(ws + 39321600);
  ushort_t* xh_pad = (ushort_t*)(ws + 9830400);      // 12*1764*512*2 = 21,676,032
  float*    gates = (float*)(ws + 39321600);
  ushort_t* w_g_r = (ushort_t*)(ws + 78643200);      // 4,718,592 B
  ushort_t* w_c_r = (ushort_t*)(ws + 83361792);      // 2,359,296 B (ends 85.7 MB)

  k_copy<<<NODESZ / 256, 256, 0, stream>>>(nodes_in, nodes);
  k_wrep<<<(C2 * 9 * C2) / 256, 256, 0, stream>>>(gw, w_g_r);
  k_wrep<<<(CC * 9 * C2) / 256, 256, 0, stream>>>(cw, w_c_r);
  for (int pass = 0; pass < 2; ++pass) {
    // ---- attention ----
    k_theta<<<dim3(5, NBB * (CC / TO)), 320, 0, stream>>>(nodes, tw, tb, th_t);
    k_to_bf_t<<<dim3(50, 8, NBB), 256, 0, stream>>>(nodes, nodes_bf_t);
    k_prep_vf<<<dim3(50, 24), 256, 0, stream>>>(nodes, vf);
    k_attn_mfma<<<dim3(25, NBB, 2), 256, 0, stream>>>(nodes_bf_t, th_t, vf, agg_t);
    // ---- conv prep (attn scratch now dead) ----
    k_pad_zero<<<(NBB * PAD * C2) / 256, 256, 0, stream>>>(xh_pad);
    k_pad_agg<<<(NBB * PP * CC) / 256, 256, 0, stream>>>(agg_t, xh_pad);
    k_pad_tr<0><<<dim3(50, 8, NBB), 256, 0, stream>>>(nodes, nullptr, xh_pad);
    // ---- gates conv ----
    k_conv_mfma<0><<<dim3(13, 4, NBB), 256, 0, stream>>>(xh_pad, w_g_r, gb, nullptr, gates);
    // ---- r*h into xh_pad high channels ----
    k_pad_tr<1><<<dim3(50, 8, NBB), 256, 0, stream>>>(nodes, gates, xh_pad);
    // ---- cand conv + fused GRU update ----
    k_conv_mfma<1><<<dim3(13, 2, NBB), 256, 0, stream>>>(xh_pad, w_c_r, cb, gates, nodes);
  }
}

// Round 13
// 1029.185 us; speedup vs baseline: 1.1619x; 1.1619x over previous
//
#include <hip/hip_runtime.h>
#include <hip/hip_bf16.h>
#include <math.h>

#define NN 3
#define BB 4
#define CC 256
#define C2 512
#define HH 40
#define WW 40
#define PP 1600
#define NBB 12                  // NN*BB
#define NODESZ (NBB*CC*PP)      // 4,915,200
#define TO 16                   // theta: output channels per block
#define PAD 1764                // 42*42 padded pixels

typedef short short8 __attribute__((ext_vector_type(8)));
typedef float f32x4 __attribute__((ext_vector_type(4)));
typedef unsigned short ushort_t;
typedef unsigned int uint_t;

__device__ __forceinline__ ushort_t f2bf(float x) {
  union { float f; uint_t u; } v; v.f = x;
  uint_t r = v.u + 0x7fff + ((v.u >> 16) & 1);
  return (ushort_t)(r >> 16);
}

__device__ __forceinline__ void async_ld16(const ushort_t* g, ushort_t* l) {
  __builtin_amdgcn_global_load_lds(
      (const __attribute__((address_space(1))) uint_t*)g,
      (__attribute__((address_space(3))) uint_t*)l, 16, 0, 0);
}

__global__ void k_copy(const float* __restrict__ in, float* __restrict__ out) {
  int i = blockIdx.x * 256 + threadIdx.x;
  out[i] = in[i];
}

// th_t[nb][p][c] (bf16) = tb[o] + sum_c tw[o,c] * nodes[nb,c,p]
__global__ void k_theta(const float* __restrict__ nodes, const float* __restrict__ tw,
                        const float* __restrict__ tb, ushort_t* __restrict__ th_t) {
  __shared__ float w[TO * CC];
  int t = threadIdx.x;
  int nb = blockIdx.y / (CC / TO);
  int o0 = (blockIdx.y % (CC / TO)) * TO;
  for (int i = t; i < TO * CC; i += 320) w[i] = tw[(o0 + (i >> 8)) * CC + (i & 255)];
  __syncthreads();
  int p = blockIdx.x * 320 + t;
  const float* src = nodes + nb * CC * PP + p;
  float acc[TO];
#pragma unroll
  for (int o = 0; o < TO; ++o) acc[o] = tb[o0 + o];
  for (int c = 0; c < CC; c += 4) {
    float v0 = src[c * PP], v1 = src[(c + 1) * PP], v2 = src[(c + 2) * PP], v3 = src[(c + 3) * PP];
#pragma unroll
    for (int o = 0; o < TO; ++o) {
      const float4 ww = *(const float4*)(w + o * CC + c);
      acc[o] += ww.x * v0 + ww.y * v1 + ww.z * v2 + ww.w * v3;
    }
  }
  size_t base = ((size_t)nb * PP + p) * CC + o0;
#pragma unroll
  for (int o = 0; o < TO; o += 2) {
    uint_t lo = f2bf(acc[o]), hi = f2bf(acc[o + 1]);
    *(uint_t*)&th_t[base + o] = lo | (hi << 16);
  }
}

// nodes [12][256][1600] fp32 -> nodes_bf_t [12][1600][256] bf16 (transpose),
// with 16B-chunk XOR swizzle within each row: c' = c ^ ((q&7)<<3).
// (Consumed only by k_attn_mfma, which un-XORs on its LDS frag reads.)
__global__ void k_to_bf_t(const float* __restrict__ src, ushort_t* __restrict__ dst) {
  __shared__ float tile[32][33];
  int nb = blockIdx.z;
  int c0 = blockIdx.y * 32;
  int pp0 = blockIdx.x * 32;
  int tx = threadIdx.x & 31, ty = threadIdx.x >> 5;
#pragma unroll
  for (int i = 0; i < 4; ++i)
    tile[ty + 8 * i][tx] = src[((size_t)nb * CC + c0 + ty + 8 * i) * PP + pp0 + tx];
  __syncthreads();
#pragma unroll
  for (int i = 0; i < 4; ++i) {
    int q = pp0 + ty + 8 * i;
    int c = c0 + tx;
    int cs = c ^ ((q & 7) << 3);
    dst[((size_t)nb * PP + q) * CC + cs] = f2bf(tile[tx][ty + 8 * i]);
  }
}

// vf frag-major bf16: vf[eb][T][nt][lane(quad,l16)][j]
//   = nodes[recv][c][p] + nodes[send][c][p],  c = 16nt + l16, p = 32T + quad*8 + j
// Each (T,nt) PV B-fragment = contiguous 1KB, one coalesced load in attn.
__global__ void k_prep_vf(const float* __restrict__ nodes, ushort_t* __restrict__ vf) {
  int T = blockIdx.x;                   // 0..49
  int eb = blockIdx.y;                  // 0..23
  int e = eb >> 2, b = eb & 3;
  int n = e >> 1, jidx = e & 1;
  int js = jidx + (jidx >= n ? 1 : 0);
  const float* s0 = nodes + (size_t)(n * BB + b) * CC * PP;
  const float* s1 = nodes + (size_t)(js * BB + b) * CC * PP;
  ushort_t* dst = vf + ((size_t)eb * 50 + T) * 8192;
  int t = threadIdx.x;
#pragma unroll
  for (int k = 0; k < 4; ++k) {
    int cid = t + 256 * k;              // 0..1023 (16 nt x 64 lanes)
    int nt = cid >> 6, l = cid & 63;
    int quad = l >> 4, l16 = l & 15;
    int c = 16 * nt + l16;
    int p = 32 * T + quad * 8;
    const float4* a0 = (const float4*)(s0 + (size_t)c * PP + p);
    const float4* a1 = (const float4*)(s1 + (size_t)c * PP + p);
    float4 x0 = a0[0], x1 = a0[1];
    float4 y0 = a1[0], y1 = a1[1];
    short8 o;
    o[0] = (short)f2bf(x0.x + y0.x); o[1] = (short)f2bf(x0.y + y0.y);
    o[2] = (short)f2bf(x0.z + y0.z); o[3] = (short)f2bf(x0.w + y0.w);
    o[4] = (short)f2bf(x1.x + y1.x); o[5] = (short)f2bf(x1.y + y1.y);
    o[6] = (short)f2bf(x1.z + y1.z); o[7] = (short)f2bf(x1.w + y1.w);
    *(short8*)(dst + (size_t)cid * 8) = o;
  }
}

// Flash attention, 64-p block, 4 waves, swapped-S softmax, XCD-swizzled.
// (unchanged from R8-R10; at its byte floor ~1.04GB / ~10TB/s.)
__global__ __launch_bounds__(256, 2) void k_attn_mfma(
    const ushort_t* __restrict__ nodes_bf_t,  // [12][1600][256] chunk-swizzled
    const ushort_t* __restrict__ th_t,        // [12][1600][256] plain
    const ushort_t* __restrict__ vf,          // [24][50][16][512] frag-major
    float* __restrict__ agg_t)                // [2][12][1600][256]
{
  __shared__ ushort_t Ej[32 * 256];   // 16 KB
  __shared__ ushort_t Sp[64 * 40];    // 5 KB (rows padded to 40 u16 = 80B)
  __shared__ float Al[64];
  __shared__ float Linv[64];

  const int t = threadIdx.x;
  const int w = t >> 6;               // 0..3
  const int l = t & 63;
  const int quad = l >> 4;
  const int l16 = l & 15;
  // ---- XCD-aware remap (perf-only; mapping assumption xcd = flat%8) ----
  const int F = blockIdx.x + 25 * (blockIdx.y + 12 * blockIdx.z);
  const int wk = (F & 7) * 75 + (F >> 3);        // bijective: 600 = 8*75
  const int p0 = (wk % 25) * 64;
  const int nb = (wk / 25) % 12;
  const int jidx = wk / 300;
  const int n = nb >> 2, b = nb & 3;
  const int e = n * 2 + jidx;
  const int js = jidx + (jidx >= n ? 1 : 0);
  const int eb = e * BB + b;

  const ushort_t* ejb = nodes_bf_t + ((size_t)(js * BB + b) * PP) * CC;  // [q][c-swz]
  const ushort_t* vbase = vf + (size_t)eb * 50 * 8192;

  // th B-frags for this wave's rows p = p0 + 16w + l16 (resident all iters)
  short8 Ath[8];
  {
    const ushort_t* arow = th_t + ((size_t)nb * PP + p0 + 16 * w + l16) * CC + quad * 8;
#pragma unroll
    for (int ks = 0; ks < 8; ++ks) Ath[ks] = *(const short8*)(arow + ks * 32);
  }

  float M = -3.0e38f, Lr = 0.f;       // per-lane: this lane's p-row state
  f32x4 O[4][4];
#pragma unroll
  for (int mt = 0; mt < 4; ++mt)
#pragma unroll
    for (int nt = 0; nt < 4; ++nt)
#pragma unroll
      for (int r = 0; r < 4; ++r) O[mt][nt][r] = 0.f;

  // prologue: stage q-tile 0 (16 chunks of 1KB, wave w does 4)
#pragma unroll
  for (int i = 0; i < 4; ++i)
    async_ld16(ejb + (4 * w + i) * 512 + l * 8, &Ej[(4 * w + i) * 512]);

  for (int T = 0; T < 50; ++T) {
    __syncthreads();   // A: Ej[T] landed (barrier drains vmcnt); Sp/Al free
    // V frags for this iter (coalesced 1KB each); vmcnt-covered by S+softmax
    short8 Bv[4];
    {
      const ushort_t* vt = vbase + (size_t)T * 8192;
#pragma unroll
      for (int nt = 0; nt < 4; ++nt)
        Bv[nt] = *(const short8*)(vt + (4 * w + nt) * 512 + l * 8);
    }
    // ---- swapped S-GEMM: S^T[q][p], rows q = quad*4+r (+16), cols p = l16 ----
    f32x4 S0, S1;
#pragma unroll
    for (int r = 0; r < 4; ++r) { S0[r] = 0.f; S1[r] = 0.f; }
#pragma unroll
    for (int ks = 0; ks < 8; ++ks) {
      int ch0 = (((ks * 4 + quad) ^ (l16 & 7)) << 3);
      short8 A0 = *(const short8*)(Ej + l16 * CC + ch0);
      short8 A1 = *(const short8*)(Ej + (16 + l16) * CC + ch0);
      S0 = __builtin_amdgcn_mfma_f32_16x16x32_bf16(A0, Ath[ks], S0, 0, 0, 0);
      S1 = __builtin_amdgcn_mfma_f32_16x16x32_bf16(A1, Ath[ks], S1, 0, 0, 0);
    }
    // ---- softmax: 8 in-lane q-values for p = p0+16w+l16; reduce across quads ----
    float m = fmaxf(fmaxf(fmaxf(S0[0], S0[1]), fmaxf(S0[2], S0[3])),
                    fmaxf(fmaxf(S1[0], S1[1]), fmaxf(S1[2], S1[3])));
    m = fmaxf(m, __shfl_xor(m, 16));
    m = fmaxf(m, __shfl_xor(m, 32));
    float Mn = fmaxf(M, m);
    float al = __expf(M - Mn);
    float e0 = __expf(S0[0] - Mn), e1 = __expf(S0[1] - Mn);
    float e2 = __expf(S0[2] - Mn), e3 = __expf(S0[3] - Mn);
    float e4 = __expf(S1[0] - Mn), e5 = __expf(S1[1] - Mn);
    float e6 = __expf(S1[2] - Mn), e7 = __expf(S1[3] - Mn);
    float s = ((e0 + e1) + (e2 + e3)) + ((e4 + e5) + (e6 + e7));
    s += __shfl_xor(s, 16);
    s += __shfl_xor(s, 32);
    Lr = Lr * al + s;
    M = Mn;
    {
      uint2 u;
      u.x = (uint_t)f2bf(e0) | ((uint_t)f2bf(e1) << 16);
      u.y = (uint_t)f2bf(e2) | ((uint_t)f2bf(e3) << 16);
      *(uint2*)&Sp[(16 * w + l16) * 40 + quad * 4] = u;
      uint2 v;
      v.x = (uint_t)f2bf(e4) | ((uint_t)f2bf(e5) << 16);
      v.y = (uint_t)f2bf(e6) | ((uint_t)f2bf(e7) << 16);
      *(uint2*)&Sp[(16 * w + l16) * 40 + 16 + quad * 4] = v;
      if (quad == 0) Al[16 * w + l16] = al;
    }
    __syncthreads();   // B: Sp/Al visible; all waves done reading Ej
    // restage Ej for T+1 (nobody reads Ej until next A, which drains vmcnt)
    if (T < 49) {
#pragma unroll
      for (int i = 0; i < 4; ++i)
        async_ld16(ejb + (size_t)(T + 1) * 8192 + (4 * w + i) * 512 + l * 8,
                   &Ej[(4 * w + i) * 512]);
    }
    // ---- rescale O (alpha of row 16mt+quad*4+r via Al broadcast reads) ----
#pragma unroll
    for (int mt = 0; mt < 4; ++mt) {
      f32x4 a4 = *(const f32x4*)&Al[16 * mt + quad * 4];
#pragma unroll
      for (int nt = 0; nt < 4; ++nt)
#pragma unroll
        for (int r = 0; r < 4; ++r) O[mt][nt][r] *= a4[r];
    }
    // ---- PV: O[p=16mt+quad*4+r][c=64w+16nt+l16] ----
#pragma unroll
    for (int mt = 0; mt < 4; ++mt) {
      short8 Ap = *(const short8*)&Sp[(16 * mt + l16) * 40 + quad * 8];
#pragma unroll
      for (int nt = 0; nt < 4; ++nt)
        O[mt][nt] = __builtin_amdgcn_mfma_f32_16x16x32_bf16(Ap, Bv[nt], O[mt][nt], 0, 0, 0);
    }
  }
  // ---- publish 1/L, then epilogue ----
  __syncthreads();
  if (quad == 0) Linv[16 * w + l16] = 1.f / Lr;
  __syncthreads();
  float* ao = agg_t + (((size_t)jidx * NBB + nb) * PP + p0) * CC;
#pragma unroll
  for (int mt = 0; mt < 4; ++mt) {
    f32x4 li = *(const f32x4*)&Linv[16 * mt + quad * 4];
#pragma unroll
    for (int r = 0; r < 4; ++r) {
      float* dst = ao + (size_t)(16 * mt + quad * 4 + r) * CC + 64 * w + l16;
#pragma unroll
      for (int nt = 0; nt < 4; ++nt) dst[16 * nt] = O[mt][nt][r] * li[r];
    }
  }
}

// ---- conv prep ----

// reorder conv weights [M][512][3][3] fp32 -> [M][9][512] bf16
__global__ void k_wrep(const float* __restrict__ w, ushort_t* __restrict__ wr) {
  int i = blockIdx.x * 256 + threadIdx.x;   // M*9*512
  int ci = i & 511;
  int rest = i >> 9;                        // co*9 + tap
  int tp = rest % 9, co = rest / 9;
  wr[i] = f2bf(w[((size_t)co * 512 + ci) * 9 + tp]);
}

// R13: zero ONLY the halo border of xh_pad (164 px/nb x 512 ch = 2 MB vs the
// old full 21.7 MB zero). Correct because the interior (y,x in 1..40) of all
// 512 channels is fully rewritten every pass by k_pad_agg (ch<256) and
// k_pad_tr (ch>=256) before any conv reads xh_pad; only the border survives,
// and it must be re-zeroed each pass (attn-phase th_t/vf writes alias xh_pad).
__global__ void k_pad_border(ushort_t* __restrict__ xpad) {
  int i = blockIdx.x * 256 + threadIdx.x;   // 12*164*512
  int c = i & 511;
  int rest = i >> 9;                        // nb*164 + bidx
  int bidx = rest % 164, nb = rest / 164;
  int y, x;
  if (bidx < 84) { y = (bidx / 42) * 41; x = bidx % 42; }      // top/bottom rows
  else { int r2 = bidx - 84; y = 1 + (r2 >> 1); x = (r2 & 1) * 41; }  // side cols
  xpad[((size_t)nb * PAD + y * 42 + x) * C2 + c] = 0;
}

// interior rows, ch 0..255 <- agg_t[0]+agg_t[1]  (both already [px][c])
__global__ void k_pad_agg(const float* __restrict__ agg_t, ushort_t* __restrict__ xpad) {
  int i = blockIdx.x * 256 + threadIdx.x;   // 12*1600*256
  int c = i & 255;
  int rest = i >> 8;
  int px = rest % PP, nb = rest / PP;
  int y = px / 40, x = px - y * 40;
  size_t src = ((size_t)nb * PP + px) * CC + c;
  float v = agg_t[src] + agg_t[(size_t)NBB * PP * CC + src];
  xpad[((size_t)nb * PAD + (y + 1) * 42 + (x + 1)) * C2 + c] = f2bf(v);
}

// interior rows, ch 256..511 <- transpose of srcA [nb][256][1600]
// MODE 0: val = h[c][px];  MODE 1: val = h[c][px] * r[c][px]
template <int MODE>
__global__ void k_pad_tr(const float* __restrict__ srcA, const float* __restrict__ srcB,
                         ushort_t* __restrict__ xpad) {
  __shared__ float tile[32][33];
  int nb = blockIdx.z;
  int c0 = blockIdx.y * 32;
  int pp0 = blockIdx.x * 32;
  int tx = threadIdx.x & 31, ty = threadIdx.x >> 5;
#pragma unroll
  for (int i = 0; i < 4; ++i) {
    int c = c0 + ty + 8 * i;
    float v = srcA[((size_t)nb * CC + c) * PP + pp0 + tx];
    if (MODE == 1) v *= srcB[((size_t)nb * C2 + c) * PP + pp0 + tx];  // r-gate
    tile[ty + 8 * i][tx] = v;
  }
  __syncthreads();
#pragma unroll
  for (int i = 0; i < 4; ++i) {
    int px = pp0 + ty + 8 * i;
    int y = px / 40, x = px - y * 40;
    xpad[((size_t)nb * PAD + (y + 1) * 42 + (x + 1)) * C2 + CC + c0 + tx] =
        f2bf(tile[tx][ty + 8 * i]);
  }
}

// Implicit-GEMM conv3x3, M=co, N=px(1600), K=9 taps x 512 ci.
// Block: 128co x 128px, 4 waves (2x2), each 64x64 (4x4 16x16x32 frags).
//
// R13: REVERTED byte-for-byte to the R10 state (best measured: 133us gates /
// ~67us cand, MfmaUtil 30%, FETCH 47MB). R11 (3-tap barriers, 80KB LDS ->
// 1 block/CU) and R12 (counted-vmcnt + sched_barrier pinning -> VGPR 128,
// occupancy 14.6%) both regressed; R10's occupancy 24.5% == 624/256 grid
// average shows it is GRID-limited at ~680 TF (~75% of the simple-structure
// ceiling). Structure: taps-inner (L1/L2 halo reuse), halo-slab staged once
// per c-chunk (B taps re-read from LDS), A+B double-buffered, 1 barrier/iter.
//
// ACT 0: out = sigmoid(acc+bias) -> gates [nb][512][1600]
// ACT 1: v = tanh(acc+bias); z = zsrc[256+co]; out(nodes) = (1-z)h + z*v
template <int ACT>
__global__ __launch_bounds__(256) void k_conv_mfma(
    const ushort_t* __restrict__ xpad,   // [12][1764][512]
    const ushort_t* __restrict__ wr,     // [M][9*512]
    const float* __restrict__ bias,      // [M]
    const float* __restrict__ zsrc,      // gates (ACT1)
    float* __restrict__ out)
{
  __shared__ ushort_t Asm[2][128 * 32];   // 2 x 8 KB   (A: 128co x 32ch)
  __shared__ ushort_t Bsl[2][256 * 32];   // 2 x 16 KB  (B slab: 256 px x 32ch)
  const int t = threadIdx.x;
  const int w = t >> 6, l = t & 63, quad = l >> 4, l16 = l & 15;
  // ---- XCD-aware remap (perf-only) ----
  const int gy = gridDim.y;                       // 4 (gates) or 2 (cand)
  const int F = blockIdx.x + 13 * (blockIdx.y + gy * blockIdx.z);
  const int cpx = (13 * gy * 12) >> 3;            // 78 or 39
  const int wk = (F & 7) * cpx + (F >> 3);        // bijective: nwg%8==0
  const int xw = wk % 13;
  const int rest = wk / 13;
  const int nb = rest % 12;
  const int m0 = (rest / 12) * 128;
  const int px0 = xw * 128;
  const int wm = (w >> 1) * 64, wn = (w & 1) * 64;

  // --- A staging source (R9 pattern): lane l covers rows 32w+lr, +16 ---
  const int lr = l >> 2;
  const int swf = (lr ^ (lr >> 2)) & 3;          // fill-side XOR swizzle
  const int lk = ((l & 3) ^ swf) * 8;            // k-part (shorts)
  const ushort_t* wsrc = wr + (size_t)(m0 + 32 * w + lr) * 4608 + lk;

  // --- B slab staging source: wave w covers slab rows [64w, 64w+64) ---
  const int slab0 = px0 + 2 * (px0 / 40);
  const int sgm = ((l >> 2) ^ (l >> 4)) & 3;
  const ushort_t* bslab_src =
      xpad + ((size_t)nb * PAD + slab0 + 64 * w + (l >> 2)) * C2 + ((l & 3) ^ sgm) * 8;

  // --- per-lane B-frag slab rows ---
  int pb[4];
#pragma unroll
  for (int nt = 0; nt < 4; ++nt) {
    int px = px0 + wn + nt * 16 + l16;
    pb[nt] = px + 2 * (px / 40) - slab0;
  }

  // --- A frag-read swizzle ---
  const int swr = (l16 ^ (l16 >> 2)) & 3;
  const int fk = ((quad ^ swr) * 8);

  f32x4 acc[4][4];
#pragma unroll
  for (int mt = 0; mt < 4; ++mt)
#pragma unroll
    for (int nt = 0; nt < 4; ++nt)
#pragma unroll
      for (int r = 0; r < 4; ++r) acc[mt][nt][r] = 0.f;

  // stageA for flat it = cc*9 + tap (taps innermost)
  auto stageA = [&](int buf, int it) {
    int ci = it / 9;
    int tap = it - ci * 9;
    const ushort_t* s = wsrc + tap * 512 + ci * 32;
    async_ld16(s, &Asm[buf][w * 1024]);
    async_ld16(s + 16 * 4608, &Asm[buf][w * 1024 + 512]);
  };
  // stageB slab for c-chunk cc: 4 asyncs/wave, 16 rows each
  auto stageB = [&](int buf, int cc) {
    const ushort_t* s = bslab_src + cc * 32;
#pragma unroll
    for (int i = 0; i < 4; ++i)
      async_ld16(s + (size_t)i * 16 * C2, &Bsl[buf][w * 2048 + i * 512]);
  };

  stageB(0, 0);
  stageA(0, 0);
  int ab = 0, bb = 0;
#pragma unroll 1
  for (int cc = 0; cc < 16; ++cc) {
#pragma unroll 1
    for (int tap = 0; tap < 9; ++tap) {
      __syncthreads();   // drains vmcnt: Asm[ab] (and slab if just staged) ready
      int nit = cc * 9 + tap + 1;
      if (nit < 144) stageA(ab ^ 1, nit);
      if (tap == 0 && cc + 1 < 16) stageB(bb ^ 1, cc + 1);
      const int ky = tap / 3;
      const int toff = ky * 42 + (tap - 3 * ky);
      short8 Af[4], Bf[4];
#pragma unroll
      for (int mt = 0; mt < 4; ++mt)
        Af[mt] = *(const short8*)(&Asm[ab][0] + (wm + mt * 16 + l16) * 32 + fk);
#pragma unroll
      for (int nt = 0; nt < 4; ++nt) {
        int R = pb[nt] + toff;
        Bf[nt] = *(const short8*)(&Bsl[bb][0] + R * 32 + ((quad ^ ((R ^ (R >> 2)) & 3)) << 3));
      }
#pragma unroll
      for (int mt = 0; mt < 4; ++mt)
#pragma unroll
        for (int nt = 0; nt < 4; ++nt)
          acc[mt][nt] = __builtin_amdgcn_mfma_f32_16x16x32_bf16(Af[mt], Bf[nt], acc[mt][nt], 0, 0, 0);
      ab ^= 1;
    }
    bb ^= 1;
  }

  // --- epilogue ---
#pragma unroll
  for (int mt = 0; mt < 4; ++mt) {
#pragma unroll
    for (int r = 0; r < 4; ++r) {
      int co = m0 + wm + mt * 16 + quad * 4 + r;
      float bv = bias[co];
#pragma unroll
      for (int nt = 0; nt < 4; ++nt) {
        int px = px0 + wn + nt * 16 + l16;
        if (px >= PP) continue;
        float v = acc[mt][nt][r] + bv;
        if (ACT == 0) {
          out[((size_t)nb * C2 + co) * PP + px] = 1.f / (1.f + __expf(-v));
        } else {
          v = tanhf(v);
          float z = zsrc[((size_t)nb * C2 + CC + co) * PP + px];
          float* hp = out + ((size_t)nb * CC + co) * PP + px;
          float h = *hp;
          *hp = (1.f - z) * h + z * v;
        }
      }
    }
  }
}

extern "C" void kernel_launch(void* const* d_in, const int* in_sizes, int n_in,
                              void* d_out, int out_size, void* d_ws, size_t ws_size,
                              hipStream_t stream) {
  const float* nodes_in = (const float*)d_in[0];
  const float* tw = (const float*)d_in[1];
  const float* tb = (const float*)d_in[2];
  const float* gw = (const float*)d_in[3];
  const float* gb = (const float*)d_in[4];
  const float* cw = (const float*)d_in[5];
  const float* cb = (const float*)d_in[6];

  float* nodes = (float*)d_out;                      // fp32 state [12][256][1600]
  char* ws = (char*)d_ws;
  // ---- layout (ws >= 98.3 MB) ----
  // attn phase: R0 nodes_bf_t 9.83 | R1 th_t 9.83 | R2 vf 19.66 | R3 agg_t 39.32
  // conv phase: R1+R2 xh_pad 21.68 | R3 gates 39.32
  // persistent:  78.64.. w_g_r 4.72 | 83.36.. w_c_r 2.36   (pass-invariant)
  ushort_t* nodes_bf_t = (ushort_t*)ws;
  ushort_t* th_t  = (ushort_t*)(ws + 9830400);
  ushort_t* vf    = (ushort_t*)(ws + 19660800);
  float*    agg_t = (float*)(ws + 39321600);
  ushort_t* xh_pad = (ushort_t*)(ws + 9830400);      // 12*1764*512*2 = 21,676,032
  float*    gates = (float*)(ws + 39321600);
  ushort_t* w_g_r = (ushort_t*)(ws + 78643200);      // 4,718,592 B
  ushort_t* w_c_r = (ushort_t*)(ws + 83361792);      // 2,359,296 B (ends 85.7 MB)

  k_copy<<<NODESZ / 256, 256, 0, stream>>>(nodes_in, nodes);
  k_wrep<<<(C2 * 9 * C2) / 256, 256, 0, stream>>>(gw, w_g_r);
  k_wrep<<<(CC * 9 * C2) / 256, 256, 0, stream>>>(cw, w_c_r);
  for (int pass = 0; pass < 2; ++pass) {
    // ---- attention ----
    k_theta<<<dim3(5, NBB * (CC / TO)), 320, 0, stream>>>(nodes, tw, tb, th_t);
    k_to_bf_t<<<dim3(50, 8, NBB), 256, 0, stream>>>(nodes, nodes_bf_t);
    k_prep_vf<<<dim3(50, 24), 256, 0, stream>>>(nodes, vf);
    k_attn_mfma<<<dim3(25, NBB, 2), 256, 0, stream>>>(nodes_bf_t, th_t, vf, agg_t);
    // ---- conv prep (attn scratch now dead); border-only zero (R13) ----
    k_pad_border<<<(NBB * 164 * C2) / 256, 256, 0, stream>>>(xh_pad);
    k_pad_agg<<<(NBB * PP * CC) / 256, 256, 0, stream>>>(agg_t, xh_pad);
    k_pad_tr<0><<<dim3(50, 8, NBB), 256, 0, stream>>>(nodes, nullptr, xh_pad);
    // ---- gates conv ----
    k_conv_mfma<0><<<dim3(13, 4, NBB), 256, 0, stream>>>(xh_pad, w_g_r, gb, nullptr, gates);
    // ---- r*h into xh_pad high channels ----
    k_pad_tr<1><<<dim3(50, 8, NBB), 256, 0, stream>>>(nodes, gates, xh_pad);
    // ---- cand conv + fused GRU update ----
    k_conv_mfma<1><<<dim3(13, 2, NBB), 256, 0, stream>>>(xh_pad, w_c_r, cb, gates, nodes);
  }
}